// Round 11
// baseline (648.858 us; speedup 1.0000x reference)
//
#include <hip/hip_runtime.h>
#include <hip/hip_fp16.h>
#include <math.h>

// ---------------------------------------------------------------------------
// GCN 2-layer inference on MI355X — binned counting-sort CSR, pre-scaled,
// fp16 feature tables. F0=512, F1=16, F2=7 (padded to 8).
//
// HW model (rounds 0-10): random-line memory ops that cross the fabric cap
// at ~25-30 G/s chip-wide; same-line lane ops within one wave instr coalesce.
// r8: LDS atomics on random addresses serialize like fabric atomics.
// r9: NT loads kill cross-iteration line reuse of strided lanes.
//
// r11 changes (latency/occupancy, zero traffic-model change):
//  - k_gemm1: split-K x2 (2 threads/row, shfl_xor combine) -> 2x waves/CU.
//  - kA_bin: edges loaded ONCE into registers (8/thread); hist+sort+stream
//    all from regs (was: two full global read phases).
//  - kB_build: bin records loaded ONCE into registers (10/thread).
// ---------------------------------------------------------------------------

#define F0 512
#define F1 16
#define F2 7
#define NPB 128     // nodes per bin
#define NBMAX 1024  // max bins (n <= 131072)
#define BINCAP 4800 // bin capacity (mean 4092 + >10 sigma for E=3.2M)
#define CH 4096     // edges per chunk in kA_bin
#define CMAX 80     // fallback bucket capacity

// ======================= binned path =======================================

__global__ __launch_bounds__(1024) void k_init2(
        const int* __restrict__ ei32, int twoE, int* __restrict__ flag,
        int* __restrict__ gcnt) {
    int t = threadIdx.x;
    if (t < 64) {                          // wave 0: dtype detect
        int idx = 1 + 2 * t;
        int v = (idx < twoE) ? ei32[idx] : 0;
        unsigned long long b = __ballot(v != 0);
        if (t == 0) *flag = (b == 0ULL) ? 1 : 0;
    }
    if (t < NBMAX) gcnt[t] = 0;
}

// Chunked LDS counting-sort binning. One workgroup = one CH-edge chunk.
// Edges are loaded once into registers (8 per thread); histogram, sort and
// stream-out all work from registers — single global read phase.
__global__ __launch_bounds__(512) void kA_bin(
        const int* __restrict__ ei32, const long long* __restrict__ ei64,
        const int* __restrict__ flag, const float* __restrict__ w,
        int* __restrict__ gcnt, int2* __restrict__ binrec, int E, int nbin) {
    __shared__ int2 sorted[CH];            // 32 KB
    __shared__ unsigned short binof[CH];   // 8 KB
    __shared__ int hist[NBMAX];            // 4 KB
    __shared__ int scanb[NBMAX];           // 4 KB (becomes excl offsets)
    __shared__ int basel[NBMAX];           // 4 KB
    __shared__ int curb[NBMAX];            // 4 KB
    int t = threadIdx.x;
    int base = blockIdx.x * CH;
    int cnt_c = E - base; if (cnt_c > CH) cnt_c = CH;
    for (int i = t; i < NBMAX; i += 512) { hist[i] = 0; curb[i] = 0; }
    bool f64 = (*flag) != 0;
    int srcv[8], dstv[8];
    float wv[8];
#pragma unroll
    for (int k = 0; k < 8; ++k) {
        int li = t + k * 512;
        dstv[k] = -1; srcv[k] = 0; wv[k] = 0.f;
        if (li < cnt_c) {
            int e = base + li;
            if (f64) { srcv[k] = (int)ei64[e]; dstv[k] = (int)ei64[(size_t)E + e]; }
            else     { srcv[k] = ei32[e];      dstv[k] = ei32[(size_t)E + e]; }
            wv[k] = w[e];
        }
    }
    __syncthreads();
    // pass 1: bin histogram from registers
#pragma unroll
    for (int k = 0; k < 8; ++k)
        if (dstv[k] >= 0) atomicAdd(&hist[dstv[k] >> 7], 1);
    __syncthreads();
    // inclusive Hillis-Steele scan over 1024 (each thread owns 2 slots)
    scanb[t] = hist[t]; scanb[t + 512] = hist[t + 512];
    __syncthreads();
    for (int off = 1; off < NBMAX; off <<= 1) {
        int a0 = (t >= off) ? scanb[t - off] : 0;
        int a1 = scanb[t + 512 - off];
        __syncthreads();
        scanb[t] += a0; scanb[t + 512] += a1;
        __syncthreads();
    }
    // inclusive -> exclusive; reserve global ranges
    {
        int e0 = scanb[t] - hist[t];
        int e1 = scanb[t + 512] - hist[t + 512];
        __syncthreads();
        scanb[t] = e0; scanb[t + 512] = e1;
        if (t < nbin)       basel[t]       = hist[t]       ? atomicAdd(&gcnt[t],       hist[t])       : 0;
        if (t + 512 < nbin) basel[t + 512] = hist[t + 512] ? atomicAdd(&gcnt[t + 512], hist[t + 512]) : 0;
    }
    __syncthreads();
    // pass 2: counting sort into LDS from registers
#pragma unroll
    for (int k = 0; k < 8; ++k) {
        if (dstv[k] >= 0) {
            int b = dstv[k] >> 7;
            int r = atomicAdd(&curb[b], 1);
            int slot = scanb[b] + r;
            sorted[slot] = make_int2((srcv[k] << 7) | (dstv[k] & 127),
                                     __float_as_int(wv[k]));
            binof[slot] = (unsigned short)b;
        }
    }
    __syncthreads();
    // stream out: consecutive lanes -> consecutive addresses (coalesced)
    for (int idx = t; idx < cnt_c; idx += 512) {
        int b = binof[idx];
        int pos = basel[b] + (idx - scanb[b]);
        if (pos < BINCAP)
            binrec[(size_t)b * BINCAP + pos] = sorted[idx];
    }
}

// Exclusive scan of clamped bin counts -> global bin bases.
__global__ __launch_bounds__(1024) void kB_scanbins(
        const int* __restrict__ gcnt, int* __restrict__ gbase, int nbin) {
    __shared__ int s[NBMAX];
    int t = threadIdx.x;
    int v = 0;
    if (t < nbin) { v = gcnt[t]; if (v > BINCAP) v = BINCAP; }
    s[t] = v;
    __syncthreads();
    for (int off = 1; off < NBMAX; off <<= 1) {
        int a = (t >= off) ? s[t - off] : 0;
        __syncthreads();
        s[t] += a;
        __syncthreads();
    }
    if (t < nbin) gbase[t] = s[t] - v;
}

// Per-bin CSR build: records loaded once into registers (10/thread);
// node histogram + weight sums + node sort from registers.
__global__ __launch_bounds__(512) void kB_build(
        const int2* __restrict__ binrec, const int* __restrict__ gcnt,
        const int* __restrict__ gbase, int2* __restrict__ ep,
        int* __restrict__ rp, int* __restrict__ cntn,
        float* __restrict__ dinv, int n) {
    __shared__ int2 srt[BINCAP];           // 37.5 KB
    __shared__ int hist[NPB];
    __shared__ float wsum[NPB];
    __shared__ int offl[NPB];
    __shared__ int curl[NPB];
    int bin = blockIdx.x;
    int t = threadIdx.x;
    int cb = gcnt[bin]; if (cb > BINCAP) cb = BINCAP;
    int gb = gbase[bin];
    const int2* rec = binrec + (size_t)bin * BINCAP;
    if (t < NPB) { hist[t] = 0; wsum[t] = 0.f; curl[t] = 0; }
    int2 rv[10];                            // 512*10 = 5120 >= BINCAP
#pragma unroll
    for (int k = 0; k < 10; ++k) {
        int i = t + k * 512;
        rv[k] = (i < cb) ? rec[i] : make_int2(-1, 0);
    }
    __syncthreads();
#pragma unroll
    for (int k = 0; k < 10; ++k) {
        if (rv[k].x >= 0) {
            int d = rv[k].x & 127;
            atomicAdd(&hist[d], 1);
            atomicAdd(&wsum[d], __int_as_float(rv[k].y));
        }
    }
    __syncthreads();
    if (t < NPB) offl[t] = hist[t];
    __syncthreads();
    for (int off = 1; off < NPB; off <<= 1) {
        int a = 0;
        if (t < NPB && t >= off) a = offl[t - off];
        __syncthreads();
        if (t < NPB) offl[t] += a;
        __syncthreads();
    }
    if (t < NPB) {
        int excl = offl[t] - hist[t];
        int node = bin * NPB + t;
        if (node < n) {
            cntn[node] = hist[t];
            rp[node] = gb + excl;
            float d = 1.f + wsum[t];       // self-loop + sum(w)
            dinv[node] = (d > 0.f) ? rsqrtf(d) : 0.f;
        }
        offl[t] = excl;
    }
    __syncthreads();
#pragma unroll
    for (int k = 0; k < 10; ++k) {
        if (rv[k].x >= 0) {
            int d = rv[k].x & 127;
            int slot = offl[d] + atomicAdd(&curl[d], 1);
            srt[slot] = make_int2((int)(((unsigned)rv[k].x) >> 7), rv[k].y);
        }
    }
    __syncthreads();
    for (int i = t; i < cb; i += 512)      // coalesced compact-CSR write
        ep[(size_t)gb + i] = srt[i];
}

// h1s = fp16( dinv * (x @ W1) ). Split-K x2: lanes (2r,2r+1) each cover half
// of K for row r, combined via one shfl_xor — 2x resident waves to hide the
// streaming-load latency. Plain cached float4 x loads (r9 lesson).
__global__ __launch_bounds__(512) void k_gemm1(
        const float* __restrict__ x, const float* __restrict__ W1,
        const float* __restrict__ dinv, __half* __restrict__ h1, int n) {
    int t = threadIdx.x;
    int row = (blockIdx.x * 512 + t) >> 1;
    int half = t & 1;
    if (row >= n) return;                  // uniform within a lane pair
    const float4* xr = (const float4*)(x + (size_t)row * F0) + half * (F0 / 8);
    const float4* wb = (const float4*)W1 + (size_t)half * (F0 / 8) * 16;
    float acc[F1];
#pragma unroll
    for (int j = 0; j < F1; ++j) acc[j] = 0.f;
#pragma unroll 4
    for (int k4 = 0; k4 < F0 / 8; ++k4) {
        float4 xv = xr[k4];
        const float4* wr = wb + k4 * 16;   // 4 rows of W1 (64 floats)
#pragma unroll
        for (int j4 = 0; j4 < 4; ++j4) {
            float4 w0 = wr[j4];
            float4 w1 = wr[4 + j4];
            float4 w2 = wr[8 + j4];
            float4 w3 = wr[12 + j4];
            acc[4*j4+0] = fmaf(xv.w, w3.x, fmaf(xv.z, w2.x, fmaf(xv.y, w1.x, fmaf(xv.x, w0.x, acc[4*j4+0]))));
            acc[4*j4+1] = fmaf(xv.w, w3.y, fmaf(xv.z, w2.y, fmaf(xv.y, w1.y, fmaf(xv.x, w0.y, acc[4*j4+1]))));
            acc[4*j4+2] = fmaf(xv.w, w3.z, fmaf(xv.z, w2.z, fmaf(xv.y, w1.z, fmaf(xv.x, w0.z, acc[4*j4+2]))));
            acc[4*j4+3] = fmaf(xv.w, w3.w, fmaf(xv.z, w2.w, fmaf(xv.y, w1.w, fmaf(xv.x, w0.w, acc[4*j4+3]))));
        }
    }
    // combine the two K-halves (lane pair)
#pragma unroll
    for (int j = 0; j < F1; ++j) acc[j] += __shfl_xor(acc[j], 1);
    if (half == 0) {
        float di = dinv[row];
        __half2 hp[8];
#pragma unroll
        for (int q = 0; q < 8; ++q)
            hp[q] = __floats2half2_rn(di * acc[2*q], di * acc[2*q+1]);
        int4 o0, o1;
        o0.x = *(int*)&hp[0]; o0.y = *(int*)&hp[1]; o0.z = *(int*)&hp[2]; o0.w = *(int*)&hp[3];
        o1.x = *(int*)&hp[4]; o1.y = *(int*)&hp[5]; o1.z = *(int*)&hp[6]; o1.w = *(int*)&hp[7];
        int4* o = (int4*)(h1 + (size_t)row * F1);
        o[0] = o0;
        o[1] = o1;
    }
}

// Gather layer 1 + fused layer-2 GEMM (16 lanes/node, shfl-xor butterfly).
// Per-node private register accumulation (r8 lesson: never LDS atomics here).
__global__ __launch_bounds__(256) void kg1(
        const int* __restrict__ rp, const int* __restrict__ cntn,
        const int2* __restrict__ ep, const __half* __restrict__ h1,
        const float* __restrict__ dinv, const float* __restrict__ b1,
        const float* __restrict__ W2, __half* __restrict__ h2, int n) {
    __shared__ float sW[F1 * 9];
    int t = threadIdx.x;
    if (t < F1 * 8) {
        int j = t >> 3, c = t & 7;
        sW[j * 9 + c] = (c < F2) ? W2[j * F2 + c] : 0.f;
    }
    __syncthreads();
    int node = blockIdx.x * 16 + (t >> 4);
    int j = t & 15;
    if (node >= n) return;
    int start = rp[node], c = cntn[node];
    const int2* b = ep + start;
    float a0 = 0.f, a1 = 0.f, a2 = 0.f, a3 = 0.f;
    int k = 0;
    for (; k + 3 < c; k += 4) {
        int2 p0 = b[k], p1 = b[k+1], p2 = b[k+2], p3 = b[k+3];
        a0 += __int_as_float(p0.y) * __half2float(h1[(size_t)p0.x * F1 + j]);
        a1 += __int_as_float(p1.y) * __half2float(h1[(size_t)p1.x * F1 + j]);
        a2 += __int_as_float(p2.y) * __half2float(h1[(size_t)p2.x * F1 + j]);
        a3 += __int_as_float(p3.y) * __half2float(h1[(size_t)p3.x * F1 + j]);
    }
    for (; k < c; ++k) {
        int2 p = b[k];
        a0 += __int_as_float(p.y) * __half2float(h1[(size_t)p.x * F1 + j]);
    }
    float di = dinv[node];
    float self = __half2float(h1[(size_t)node * F1 + j]);
    float g = di * ((a0 + a1) + (a2 + a3) + self) + b1[j];
    g = fmaxf(g, 0.f);                     // fused ReLU
    float hv[8];
#pragma unroll
    for (int cc = 0; cc < 8; ++cc) hv[cc] = g * sW[j * 9 + cc];
#pragma unroll
    for (int off = 1; off < 16; off <<= 1) {
#pragma unroll
        for (int cc = 0; cc < 8; ++cc) hv[cc] += __shfl_xor(hv[cc], off, 16);
    }
    float o = hv[0];
#pragma unroll
    for (int cc = 1; cc < 8; ++cc) if (j == cc) o = hv[cc];
    if (j < 8) h2[(size_t)node * 8 + j] = __float2half(di * o);  // h2s
}

// Gather layer 2 + bias + log_softmax (8 lanes/node). h2 pre-scaled fp16.
__global__ __launch_bounds__(256) void kg2(
        const int* __restrict__ rp, const int* __restrict__ cntn,
        const int2* __restrict__ ep, const __half* __restrict__ h2,
        const float* __restrict__ dinv, const float* __restrict__ b2,
        float* __restrict__ out, int n) {
    int t = threadIdx.x;
    int node = blockIdx.x * 32 + (t >> 3);
    int c = t & 7;
    if (node >= n) return;
    int start = rp[node], cd = cntn[node];
    const int2* b = ep + start;
    float a0 = 0.f, a1 = 0.f, a2 = 0.f, a3 = 0.f;
    int k = 0;
    for (; k + 3 < cd; k += 4) {
        int2 p0 = b[k], p1 = b[k+1], p2 = b[k+2], p3 = b[k+3];
        a0 += __int_as_float(p0.y) * __half2float(h2[(size_t)p0.x * 8 + c]);
        a1 += __int_as_float(p1.y) * __half2float(h2[(size_t)p1.x * 8 + c]);
        a2 += __int_as_float(p2.y) * __half2float(h2[(size_t)p2.x * 8 + c]);
        a3 += __int_as_float(p3.y) * __half2float(h2[(size_t)p3.x * 8 + c]);
    }
    for (; k < cd; ++k) {
        int2 p = b[k];
        a0 += __int_as_float(p.y) * __half2float(h2[(size_t)p.x * 8 + c]);
    }
    float di = dinv[node];
    float self = __half2float(h2[(size_t)node * 8 + c]);
    float v = di * ((a0 + a1) + (a2 + a3) + self) + ((c < F2) ? b2[c] : 0.f);
    float vm = (c < F2) ? v : -3.0e38f;
    vm = fmaxf(vm, __shfl_xor(vm, 1, 8));
    vm = fmaxf(vm, __shfl_xor(vm, 2, 8));
    vm = fmaxf(vm, __shfl_xor(vm, 4, 8));
    float ex = (c < F2) ? __expf(v - vm) : 0.f;
    float s = ex;
    s += __shfl_xor(s, 1, 8);
    s += __shfl_xor(s, 2, 8);
    s += __shfl_xor(s, 4, 8);
    float ls = __logf(s) + vm;
    if (c < F2) out[(size_t)node * F2 + c] = v - ls;
}

// ================= fallback path (bucket CSR, pre-scaled fp16) =============

__global__ __launch_bounds__(256) void kf_init(
        const int* __restrict__ ei32, int twoE, int* __restrict__ flag,
        int* __restrict__ cur, int n) {
    if (blockIdx.x == 0 && threadIdx.x < 64) {
        int idx = 1 + 2 * (int)threadIdx.x;
        int v = (idx < twoE) ? ei32[idx] : 0;
        unsigned long long b = __ballot(v != 0);
        if (threadIdx.x == 0) *flag = (b == 0ULL) ? 1 : 0;
    }
    int i = blockIdx.x * 256 + threadIdx.x;
    if (i < n) cur[i] = 0;
}

__global__ __launch_bounds__(256) void kf_fill(
        const int* __restrict__ ei32, const long long* __restrict__ ei64,
        const int* __restrict__ flag, const float* __restrict__ w,
        int* __restrict__ cur, int2* __restrict__ ep, int E) {
    int e = blockIdx.x * 256 + threadIdx.x;
    if (e >= E) return;
    int src, dst;
    if (*flag) { src = (int)ei64[e]; dst = (int)ei64[(size_t)E + e]; }
    else       { src = ei32[e];      dst = ei32[(size_t)E + e]; }
    int pos = atomicAdd(&cur[dst], 1);
    if (pos < CMAX) {
        int2 p;
        p.x = src;
        p.y = __float_as_int(w[e]);
        ep[(size_t)dst * CMAX + pos] = p;
    }
}

__global__ __launch_bounds__(256) void kf_degdinv(
        const int* __restrict__ cur, const int2* __restrict__ ep,
        float* __restrict__ dinv, int n) {
    int t = threadIdx.x;
    int node = blockIdx.x * 16 + (t >> 4);
    int j = t & 15;
    if (node >= n) return;
    int c = cur[node]; if (c > CMAX) c = CMAX;
    const int2* b = ep + (size_t)node * CMAX;
    float s = 0.f;
    for (int k = j; k < c; k += 16) s += __int_as_float(b[k].y);
    s += __shfl_xor(s, 1, 16);
    s += __shfl_xor(s, 2, 16);
    s += __shfl_xor(s, 4, 16);
    s += __shfl_xor(s, 8, 16);
    if (j == 0) {
        float d = 1.f + s;
        dinv[node] = (d > 0.f) ? rsqrtf(d) : 0.f;
    }
}

__global__ __launch_bounds__(256) void kf_gather1(
        const int* __restrict__ cur, const int2* __restrict__ ep,
        const __half* __restrict__ h1, const float* __restrict__ dinv,
        const float* __restrict__ b1, const float* __restrict__ W2,
        __half* __restrict__ h2, int n) {
    __shared__ float sW[F1 * 9];
    int t = threadIdx.x;
    if (t < F1 * 8) {
        int j = t >> 3, c = t & 7;
        sW[j * 9 + c] = (c < F2) ? W2[j * F2 + c] : 0.f;
    }
    __syncthreads();
    int node = blockIdx.x * 16 + (t >> 4);
    int j = t & 15;
    if (node >= n) return;
    int c = cur[node]; if (c > CMAX) c = CMAX;
    const int2* b = ep + (size_t)node * CMAX;
    float a0 = 0.f, a1 = 0.f;
    int k = 0;
    for (; k + 1 < c; k += 2) {
        int2 p0 = b[k], p1 = b[k + 1];
        a0 += __int_as_float(p0.y) * __half2float(h1[(size_t)p0.x * F1 + j]);
        a1 += __int_as_float(p1.y) * __half2float(h1[(size_t)p1.x * F1 + j]);
    }
    if (k < c) {
        int2 p = b[k];
        a0 += __int_as_float(p.y) * __half2float(h1[(size_t)p.x * F1 + j]);
    }
    float di = dinv[node];
    float g = di * (a0 + a1 + __half2float(h1[(size_t)node * F1 + j])) + b1[j];
    g = fmaxf(g, 0.f);
    float hv[8];
#pragma unroll
    for (int cc = 0; cc < 8; ++cc) hv[cc] = g * sW[j * 9 + cc];
#pragma unroll
    for (int off = 1; off < 16; off <<= 1) {
#pragma unroll
        for (int cc = 0; cc < 8; ++cc) hv[cc] += __shfl_xor(hv[cc], off, 16);
    }
    float o = hv[0];
#pragma unroll
    for (int cc = 1; cc < 8; ++cc) if (j == cc) o = hv[cc];
    if (j < 8) h2[(size_t)node * 8 + j] = __float2half(di * o);
}

__global__ __launch_bounds__(256) void kf_gather2(
        const int* __restrict__ cur, const int2* __restrict__ ep,
        const __half* __restrict__ h2, const float* __restrict__ dinv,
        const float* __restrict__ b2, float* __restrict__ out, int n) {
    int t = threadIdx.x;
    int node = blockIdx.x * 32 + (t >> 3);
    int c = t & 7;
    if (node >= n) return;
    int cd = cur[node]; if (cd > CMAX) cd = CMAX;
    const int2* b = ep + (size_t)node * CMAX;
    float a0 = 0.f, a1 = 0.f;
    int k = 0;
    for (; k + 1 < cd; k += 2) {
        int2 p0 = b[k], p1 = b[k + 1];
        a0 += __int_as_float(p0.y) * __half2float(h2[(size_t)p0.x * 8 + c]);
        a1 += __int_as_float(p1.y) * __half2float(h2[(size_t)p1.x * 8 + c]);
    }
    if (k < cd) {
        int2 p = b[k];
        a0 += __int_as_float(p.y) * __half2float(h2[(size_t)p.x * 8 + c]);
    }
    float di = dinv[node];
    float v = di * (a0 + a1 + __half2float(h2[(size_t)node * 8 + c]))
              + ((c < F2) ? b2[c] : 0.f);
    float vm = (c < F2) ? v : -3.0e38f;
    vm = fmaxf(vm, __shfl_xor(vm, 1, 8));
    vm = fmaxf(vm, __shfl_xor(vm, 2, 8));
    vm = fmaxf(vm, __shfl_xor(vm, 4, 8));
    float ex = (c < F2) ? __expf(v - vm) : 0.f;
    float s = ex;
    s += __shfl_xor(s, 1, 8);
    s += __shfl_xor(s, 2, 8);
    s += __shfl_xor(s, 4, 8);
    float ls = __logf(s) + vm;
    if (c < F2) out[(size_t)node * F2 + c] = v - ls;
}

// ===========================================================================

extern "C" void kernel_launch(void* const* d_in, const int* in_sizes, int n_in,
                              void* d_out, int out_size, void* d_ws, size_t ws_size,
                              hipStream_t stream) {
    const float* x  = (const float*)d_in[0];
    const int* ei32 = (const int*)d_in[1];
    const long long* ei64 = (const long long*)d_in[1];
    const float* w  = (const float*)d_in[2];
    const float* W1 = (const float*)d_in[3];
    const float* b1 = (const float*)d_in[4];
    const float* W2 = (const float*)d_in[5];
    const float* b2 = (const float*)d_in[6];
    float* out = (float*)d_out;

    const int n = in_sizes[0] / F0;       // 100000
    const int E = in_sizes[2];            // 3200000
    const int B = 256;

    const int nbin = (n + NPB - 1) / NPB; // 782
    double mean = (double)E / (double)nbin;
    bool ok_bin = (n <= (1 << 17)) && (nbin <= NBMAX) &&
                  (mean + 8.0 * sqrt(mean) + 64.0 <= (double)BINCAP);

    size_t binrec_b = (size_t)nbin * BINCAP * sizeof(int2);
    size_t alias_b  = (size_t)n * (F1 + 8) * sizeof(__half);  // h1h + h2h
    size_t reg0     = binrec_b > alias_b ? binrec_b : alias_b;
    size_t need_bin = reg0 + (size_t)E * sizeof(int2)
                    + (size_t)n * 3 * 4 + (size_t)NBMAX * 8 + 256;

    if (ok_bin && ws_size >= need_bin) {
        // -------- binned counting-sort CSR path --------
        char* p = (char*)d_ws;
        int2* binrec = (int2*)p;                         // dead after kB_build
        __half* h1   = (__half*)p;                       // aliases binrec (3.2MB)
        __half* h2   = h1 + (size_t)n * F1;              // 1.6MB
        int2* ep     = (int2*)(p + reg0);                // E*8B
        float* dinv  = (float*)(ep + E);                 // n
        int* rp      = (int*)(dinv + n);                 // n
        int* cntn    = rp + n;                           // n
        int* gcnt    = cntn + n;                         // NBMAX
        int* gbase   = gcnt + NBMAX;                     // NBMAX
        int* flag    = gbase + NBMAX;                    // 1

        k_init2<<<1, 1024, 0, stream>>>(ei32, 2 * E, flag, gcnt);
        kA_bin<<<(E + CH - 1) / CH, 512, 0, stream>>>(
            ei32, ei64, flag, w, gcnt, binrec, E, nbin);
        kB_scanbins<<<1, 1024, 0, stream>>>(gcnt, gbase, nbin);
        kB_build<<<nbin, 512, 0, stream>>>(binrec, gcnt, gbase, ep, rp, cntn, dinv, n);
        k_gemm1<<<(2 * n + 511) / 512, 512, 0, stream>>>(x, W1, dinv, h1, n);
        kg1<<<(n + 15) / 16, B, 0, stream>>>(rp, cntn, ep, h1, dinv, b1, W2, h2, n);
        kg2<<<(n + 31) / 32, B, 0, stream>>>(rp, cntn, ep, h2, dinv, b2, out, n);
    } else {
        // -------- fallback: bucket CSR --------
        const int nbN = (n + B - 1) / B;
        const int nbE = (E + B - 1) / B;
        int2* ep    = (int2*)d_ws;                       // n*CMAX*8B
        __half* h1  = (__half*)(ep + (size_t)n * CMAX);  // n*16 halves
        __half* h2  = h1 + (size_t)n * F1;               // n*8 halves
        float* dinv = (float*)(h2 + (size_t)n * 8);      // n
        int* cur    = (int*)(dinv + n);                  // n
        int* flag   = cur + n;                           // 1

        kf_init<<<nbN, B, 0, stream>>>(ei32, 2 * E, flag, cur, n);
        kf_fill<<<nbE, B, 0, stream>>>(ei32, ei64, flag, w, cur, ep, E);
        kf_degdinv<<<(n + 15) / 16, B, 0, stream>>>(cur, ep, dinv, n);
        k_gemm1<<<(2 * n + 511) / 512, 512, 0, stream>>>(x, W1, dinv, h1, n);
        kf_gather1<<<(n + 15) / 16, B, 0, stream>>>(cur, ep, h1, dinv, b1, W2, h2, n);
        kf_gather2<<<(n + 31) / 32, B, 0, stream>>>(cur, ep, h2, dinv, b2, out, n);
    }
}

// Round 12
// 475.921 us; speedup vs baseline: 1.3634x; 1.3634x over previous
//
#include <hip/hip_runtime.h>
#include <hip/hip_fp16.h>
#include <math.h>

// ---------------------------------------------------------------------------
// GCN 2-layer inference on MI355X — binned counting-sort CSR, pre-scaled,
// fp16 feature tables. F0=512, F1=16, F2=7 (padded to 8).
//
// HW model (rounds 0-11): random-line memory ops that cross the fabric cap
// at ~25-30 G/s chip-wide; same-line lane ops within one wave instr coalesce.
// r8: LDS atomics on random addresses serialize like fabric atomics.
// r9: NT loads kill cross-iteration line reuse of strided lanes.
// r11: k_gemm1's speed depends on WAVE-UNIFORM W1 addresses (compiler
//      scalarizes to s_load/SGPR; 96 SGPRs). Any per-lane term in the weight
//      address breaks scalarization -> 17 VMEM instrs/iter -> 281us. Split-K
//      reverted; kA_bin/kB_build register-load versions kept (-61us).
// ---------------------------------------------------------------------------

#define F0 512
#define F1 16
#define F2 7
#define NPB 128     // nodes per bin
#define NBMAX 1024  // max bins (n <= 131072)
#define BINCAP 4800 // bin capacity (mean 4092 + >10 sigma for E=3.2M)
#define CH 4096     // edges per chunk in kA_bin
#define CMAX 80     // fallback bucket capacity

// ======================= binned path =======================================

__global__ __launch_bounds__(1024) void k_init2(
        const int* __restrict__ ei32, int twoE, int* __restrict__ flag,
        int* __restrict__ gcnt) {
    int t = threadIdx.x;
    if (t < 64) {                          // wave 0: dtype detect
        int idx = 1 + 2 * t;
        int v = (idx < twoE) ? ei32[idx] : 0;
        unsigned long long b = __ballot(v != 0);
        if (t == 0) *flag = (b == 0ULL) ? 1 : 0;
    }
    if (t < NBMAX) gcnt[t] = 0;
}

// Chunked LDS counting-sort binning. One workgroup = one CH-edge chunk.
// Edges loaded once into registers (8/thread); hist+sort+stream from regs.
__global__ __launch_bounds__(512) void kA_bin(
        const int* __restrict__ ei32, const long long* __restrict__ ei64,
        const int* __restrict__ flag, const float* __restrict__ w,
        int* __restrict__ gcnt, int2* __restrict__ binrec, int E, int nbin) {
    __shared__ int2 sorted[CH];            // 32 KB
    __shared__ unsigned short binof[CH];   // 8 KB
    __shared__ int hist[NBMAX];            // 4 KB
    __shared__ int scanb[NBMAX];           // 4 KB (becomes excl offsets)
    __shared__ int basel[NBMAX];           // 4 KB
    __shared__ int curb[NBMAX];            // 4 KB
    int t = threadIdx.x;
    int base = blockIdx.x * CH;
    int cnt_c = E - base; if (cnt_c > CH) cnt_c = CH;
    for (int i = t; i < NBMAX; i += 512) { hist[i] = 0; curb[i] = 0; }
    bool f64 = (*flag) != 0;
    int srcv[8], dstv[8];
    float wv[8];
#pragma unroll
    for (int k = 0; k < 8; ++k) {
        int li = t + k * 512;
        dstv[k] = -1; srcv[k] = 0; wv[k] = 0.f;
        if (li < cnt_c) {
            int e = base + li;
            if (f64) { srcv[k] = (int)ei64[e]; dstv[k] = (int)ei64[(size_t)E + e]; }
            else     { srcv[k] = ei32[e];      dstv[k] = ei32[(size_t)E + e]; }
            wv[k] = w[e];
        }
    }
    __syncthreads();
    // pass 1: bin histogram from registers
#pragma unroll
    for (int k = 0; k < 8; ++k)
        if (dstv[k] >= 0) atomicAdd(&hist[dstv[k] >> 7], 1);
    __syncthreads();
    // inclusive Hillis-Steele scan over 1024 (each thread owns 2 slots)
    scanb[t] = hist[t]; scanb[t + 512] = hist[t + 512];
    __syncthreads();
    for (int off = 1; off < NBMAX; off <<= 1) {
        int a0 = (t >= off) ? scanb[t - off] : 0;
        int a1 = scanb[t + 512 - off];
        __syncthreads();
        scanb[t] += a0; scanb[t + 512] += a1;
        __syncthreads();
    }
    // inclusive -> exclusive; reserve global ranges
    {
        int e0 = scanb[t] - hist[t];
        int e1 = scanb[t + 512] - hist[t + 512];
        __syncthreads();
        scanb[t] = e0; scanb[t + 512] = e1;
        if (t < nbin)       basel[t]       = hist[t]       ? atomicAdd(&gcnt[t],       hist[t])       : 0;
        if (t + 512 < nbin) basel[t + 512] = hist[t + 512] ? atomicAdd(&gcnt[t + 512], hist[t + 512]) : 0;
    }
    __syncthreads();
    // pass 2: counting sort into LDS from registers
#pragma unroll
    for (int k = 0; k < 8; ++k) {
        if (dstv[k] >= 0) {
            int b = dstv[k] >> 7;
            int r = atomicAdd(&curb[b], 1);
            int slot = scanb[b] + r;
            sorted[slot] = make_int2((srcv[k] << 7) | (dstv[k] & 127),
                                     __float_as_int(wv[k]));
            binof[slot] = (unsigned short)b;
        }
    }
    __syncthreads();
    // stream out: consecutive lanes -> consecutive addresses (coalesced)
    for (int idx = t; idx < cnt_c; idx += 512) {
        int b = binof[idx];
        int pos = basel[b] + (idx - scanb[b]);
        if (pos < BINCAP)
            binrec[(size_t)b * BINCAP + pos] = sorted[idx];
    }
}

// Exclusive scan of clamped bin counts -> global bin bases.
__global__ __launch_bounds__(1024) void kB_scanbins(
        const int* __restrict__ gcnt, int* __restrict__ gbase, int nbin) {
    __shared__ int s[NBMAX];
    int t = threadIdx.x;
    int v = 0;
    if (t < nbin) { v = gcnt[t]; if (v > BINCAP) v = BINCAP; }
    s[t] = v;
    __syncthreads();
    for (int off = 1; off < NBMAX; off <<= 1) {
        int a = (t >= off) ? s[t - off] : 0;
        __syncthreads();
        s[t] += a;
        __syncthreads();
    }
    if (t < nbin) gbase[t] = s[t] - v;
}

// Per-bin CSR build: records loaded once into registers (10/thread);
// node histogram + weight sums + node sort from registers.
__global__ __launch_bounds__(512) void kB_build(
        const int2* __restrict__ binrec, const int* __restrict__ gcnt,
        const int* __restrict__ gbase, int2* __restrict__ ep,
        int* __restrict__ rp, int* __restrict__ cntn,
        float* __restrict__ dinv, int n) {
    __shared__ int2 srt[BINCAP];           // 37.5 KB
    __shared__ int hist[NPB];
    __shared__ float wsum[NPB];
    __shared__ int offl[NPB];
    __shared__ int curl[NPB];
    int bin = blockIdx.x;
    int t = threadIdx.x;
    int cb = gcnt[bin]; if (cb > BINCAP) cb = BINCAP;
    int gb = gbase[bin];
    const int2* rec = binrec + (size_t)bin * BINCAP;
    if (t < NPB) { hist[t] = 0; wsum[t] = 0.f; curl[t] = 0; }
    int2 rv[10];                            // 512*10 = 5120 >= BINCAP
#pragma unroll
    for (int k = 0; k < 10; ++k) {
        int i = t + k * 512;
        rv[k] = (i < cb) ? rec[i] : make_int2(-1, 0);
    }
    __syncthreads();
#pragma unroll
    for (int k = 0; k < 10; ++k) {
        if (rv[k].x >= 0) {
            int d = rv[k].x & 127;
            atomicAdd(&hist[d], 1);
            atomicAdd(&wsum[d], __int_as_float(rv[k].y));
        }
    }
    __syncthreads();
    if (t < NPB) offl[t] = hist[t];
    __syncthreads();
    for (int off = 1; off < NPB; off <<= 1) {
        int a = 0;
        if (t < NPB && t >= off) a = offl[t - off];
        __syncthreads();
        if (t < NPB) offl[t] += a;
        __syncthreads();
    }
    if (t < NPB) {
        int excl = offl[t] - hist[t];
        int node = bin * NPB + t;
        if (node < n) {
            cntn[node] = hist[t];
            rp[node] = gb + excl;
            float d = 1.f + wsum[t];       // self-loop + sum(w)
            dinv[node] = (d > 0.f) ? rsqrtf(d) : 0.f;
        }
        offl[t] = excl;
    }
    __syncthreads();
#pragma unroll
    for (int k = 0; k < 10; ++k) {
        if (rv[k].x >= 0) {
            int d = rv[k].x & 127;
            int slot = offl[d] + atomicAdd(&curl[d], 1);
            srt[slot] = make_int2((int)(((unsigned)rv[k].x) >> 7), rv[k].y);
        }
    }
    __syncthreads();
    for (int i = t; i < cb; i += 512)      // coalesced compact-CSR write
        ep[(size_t)gb + i] = srt[i];
}

// h1s = fp16( dinv * (x @ W1) ). One thread per row, 16 VGPR accumulators,
// W1 via WAVE-UNIFORM addresses (compiler scalarizes to s_load -> SGPR;
// r11 lesson: any per-lane term in the W address breaks this). Plain cached
// float4 x loads (r9 lesson: no NT hints on partially-consumed lines).
__global__ __launch_bounds__(256) void k_gemm1(
        const float* __restrict__ x, const float* __restrict__ W1,
        const float* __restrict__ dinv, __half* __restrict__ h1, int n) {
    int row = blockIdx.x * 256 + threadIdx.x;
    if (row >= n) return;
    const float4* xr = (const float4*)(x + (size_t)row * F0);
    const float4* wb = (const float4*)W1;
    float acc[F1];
#pragma unroll
    for (int j = 0; j < F1; ++j) acc[j] = 0.f;
#pragma unroll 2
    for (int k4 = 0; k4 < F0 / 4; ++k4) {
        float4 xv = xr[k4];
        const float4* wr = wb + k4 * 16;   // rows 4k4..4k4+3 of W1 (64 floats)
#pragma unroll
        for (int j4 = 0; j4 < 4; ++j4) {
            float4 w0 = wr[j4];
            float4 w1 = wr[4 + j4];
            float4 w2 = wr[8 + j4];
            float4 w3 = wr[12 + j4];
            acc[4*j4+0] = fmaf(xv.w, w3.x, fmaf(xv.z, w2.x, fmaf(xv.y, w1.x, fmaf(xv.x, w0.x, acc[4*j4+0]))));
            acc[4*j4+1] = fmaf(xv.w, w3.y, fmaf(xv.z, w2.y, fmaf(xv.y, w1.y, fmaf(xv.x, w0.y, acc[4*j4+1]))));
            acc[4*j4+2] = fmaf(xv.w, w3.z, fmaf(xv.z, w2.z, fmaf(xv.y, w1.z, fmaf(xv.x, w0.z, acc[4*j4+2]))));
            acc[4*j4+3] = fmaf(xv.w, w3.w, fmaf(xv.z, w2.w, fmaf(xv.y, w1.w, fmaf(xv.x, w0.w, acc[4*j4+3]))));
        }
    }
    float di = dinv[row];
    __half2 hp[8];
#pragma unroll
    for (int q = 0; q < 8; ++q)
        hp[q] = __floats2half2_rn(di * acc[2*q], di * acc[2*q+1]);
    int4 o0, o1;
    o0.x = *(int*)&hp[0]; o0.y = *(int*)&hp[1]; o0.z = *(int*)&hp[2]; o0.w = *(int*)&hp[3];
    o1.x = *(int*)&hp[4]; o1.y = *(int*)&hp[5]; o1.z = *(int*)&hp[6]; o1.w = *(int*)&hp[7];
    int4* o = (int4*)(h1 + (size_t)row * F1);
    o[0] = o0;
    o[1] = o1;
}

// Gather layer 1 + fused layer-2 GEMM (16 lanes/node, shfl-xor butterfly).
// Per-node private register accumulation (r8 lesson: never LDS atomics here).
__global__ __launch_bounds__(256) void kg1(
        const int* __restrict__ rp, const int* __restrict__ cntn,
        const int2* __restrict__ ep, const __half* __restrict__ h1,
        const float* __restrict__ dinv, const float* __restrict__ b1,
        const float* __restrict__ W2, __half* __restrict__ h2, int n) {
    __shared__ float sW[F1 * 9];
    int t = threadIdx.x;
    if (t < F1 * 8) {
        int j = t >> 3, c = t & 7;
        sW[j * 9 + c] = (c < F2) ? W2[j * F2 + c] : 0.f;
    }
    __syncthreads();
    int node = blockIdx.x * 16 + (t >> 4);
    int j = t & 15;
    if (node >= n) return;
    int start = rp[node], c = cntn[node];
    const int2* b = ep + start;
    float a0 = 0.f, a1 = 0.f, a2 = 0.f, a3 = 0.f;
    int k = 0;
    for (; k + 3 < c; k += 4) {
        int2 p0 = b[k], p1 = b[k+1], p2 = b[k+2], p3 = b[k+3];
        a0 += __int_as_float(p0.y) * __half2float(h1[(size_t)p0.x * F1 + j]);
        a1 += __int_as_float(p1.y) * __half2float(h1[(size_t)p1.x * F1 + j]);
        a2 += __int_as_float(p2.y) * __half2float(h1[(size_t)p2.x * F1 + j]);
        a3 += __int_as_float(p3.y) * __half2float(h1[(size_t)p3.x * F1 + j]);
    }
    for (; k < c; ++k) {
        int2 p = b[k];
        a0 += __int_as_float(p.y) * __half2float(h1[(size_t)p.x * F1 + j]);
    }
    float di = dinv[node];
    float self = __half2float(h1[(size_t)node * F1 + j]);
    float g = di * ((a0 + a1) + (a2 + a3) + self) + b1[j];
    g = fmaxf(g, 0.f);                     // fused ReLU
    float hv[8];
#pragma unroll
    for (int cc = 0; cc < 8; ++cc) hv[cc] = g * sW[j * 9 + cc];
#pragma unroll
    for (int off = 1; off < 16; off <<= 1) {
#pragma unroll
        for (int cc = 0; cc < 8; ++cc) hv[cc] += __shfl_xor(hv[cc], off, 16);
    }
    float o = hv[0];
#pragma unroll
    for (int cc = 1; cc < 8; ++cc) if (j == cc) o = hv[cc];
    if (j < 8) h2[(size_t)node * 8 + j] = __float2half(di * o);  // h2s
}

// Gather layer 2 + bias + log_softmax (8 lanes/node). h2 pre-scaled fp16.
__global__ __launch_bounds__(256) void kg2(
        const int* __restrict__ rp, const int* __restrict__ cntn,
        const int2* __restrict__ ep, const __half* __restrict__ h2,
        const float* __restrict__ dinv, const float* __restrict__ b2,
        float* __restrict__ out, int n) {
    int t = threadIdx.x;
    int node = blockIdx.x * 32 + (t >> 3);
    int c = t & 7;
    if (node >= n) return;
    int start = rp[node], cd = cntn[node];
    const int2* b = ep + start;
    float a0 = 0.f, a1 = 0.f, a2 = 0.f, a3 = 0.f;
    int k = 0;
    for (; k + 3 < cd; k += 4) {
        int2 p0 = b[k], p1 = b[k+1], p2 = b[k+2], p3 = b[k+3];
        a0 += __int_as_float(p0.y) * __half2float(h2[(size_t)p0.x * 8 + c]);
        a1 += __int_as_float(p1.y) * __half2float(h2[(size_t)p1.x * 8 + c]);
        a2 += __int_as_float(p2.y) * __half2float(h2[(size_t)p2.x * 8 + c]);
        a3 += __int_as_float(p3.y) * __half2float(h2[(size_t)p3.x * 8 + c]);
    }
    for (; k < cd; ++k) {
        int2 p = b[k];
        a0 += __int_as_float(p.y) * __half2float(h2[(size_t)p.x * 8 + c]);
    }
    float di = dinv[node];
    float self = __half2float(h2[(size_t)node * 8 + c]);
    float v = di * ((a0 + a1) + (a2 + a3) + self) + ((c < F2) ? b2[c] : 0.f);
    float vm = (c < F2) ? v : -3.0e38f;
    vm = fmaxf(vm, __shfl_xor(vm, 1, 8));
    vm = fmaxf(vm, __shfl_xor(vm, 2, 8));
    vm = fmaxf(vm, __shfl_xor(vm, 4, 8));
    float ex = (c < F2) ? __expf(v - vm) : 0.f;
    float s = ex;
    s += __shfl_xor(s, 1, 8);
    s += __shfl_xor(s, 2, 8);
    s += __shfl_xor(s, 4, 8);
    float ls = __logf(s) + vm;
    if (c < F2) out[(size_t)node * F2 + c] = v - ls;
}

// ================= fallback path (bucket CSR, pre-scaled fp16) =============

__global__ __launch_bounds__(256) void kf_init(
        const int* __restrict__ ei32, int twoE, int* __restrict__ flag,
        int* __restrict__ cur, int n) {
    if (blockIdx.x == 0 && threadIdx.x < 64) {
        int idx = 1 + 2 * (int)threadIdx.x;
        int v = (idx < twoE) ? ei32[idx] : 0;
        unsigned long long b = __ballot(v != 0);
        if (threadIdx.x == 0) *flag = (b == 0ULL) ? 1 : 0;
    }
    int i = blockIdx.x * 256 + threadIdx.x;
    if (i < n) cur[i] = 0;
}

__global__ __launch_bounds__(256) void kf_fill(
        const int* __restrict__ ei32, const long long* __restrict__ ei64,
        const int* __restrict__ flag, const float* __restrict__ w,
        int* __restrict__ cur, int2* __restrict__ ep, int E) {
    int e = blockIdx.x * 256 + threadIdx.x;
    if (e >= E) return;
    int src, dst;
    if (*flag) { src = (int)ei64[e]; dst = (int)ei64[(size_t)E + e]; }
    else       { src = ei32[e];      dst = ei32[(size_t)E + e]; }
    int pos = atomicAdd(&cur[dst], 1);
    if (pos < CMAX) {
        int2 p;
        p.x = src;
        p.y = __float_as_int(w[e]);
        ep[(size_t)dst * CMAX + pos] = p;
    }
}

__global__ __launch_bounds__(256) void kf_degdinv(
        const int* __restrict__ cur, const int2* __restrict__ ep,
        float* __restrict__ dinv, int n) {
    int t = threadIdx.x;
    int node = blockIdx.x * 16 + (t >> 4);
    int j = t & 15;
    if (node >= n) return;
    int c = cur[node]; if (c > CMAX) c = CMAX;
    const int2* b = ep + (size_t)node * CMAX;
    float s = 0.f;
    for (int k = j; k < c; k += 16) s += __int_as_float(b[k].y);
    s += __shfl_xor(s, 1, 16);
    s += __shfl_xor(s, 2, 16);
    s += __shfl_xor(s, 4, 16);
    s += __shfl_xor(s, 8, 16);
    if (j == 0) {
        float d = 1.f + s;
        dinv[node] = (d > 0.f) ? rsqrtf(d) : 0.f;
    }
}

__global__ __launch_bounds__(256) void kf_gather1(
        const int* __restrict__ cur, const int2* __restrict__ ep,
        const __half* __restrict__ h1, const float* __restrict__ dinv,
        const float* __restrict__ b1, const float* __restrict__ W2,
        __half* __restrict__ h2, int n) {
    __shared__ float sW[F1 * 9];
    int t = threadIdx.x;
    if (t < F1 * 8) {
        int j = t >> 3, c = t & 7;
        sW[j * 9 + c] = (c < F2) ? W2[j * F2 + c] : 0.f;
    }
    __syncthreads();
    int node = blockIdx.x * 16 + (t >> 4);
    int j = t & 15;
    if (node >= n) return;
    int c = cur[node]; if (c > CMAX) c = CMAX;
    const int2* b = ep + (size_t)node * CMAX;
    float a0 = 0.f, a1 = 0.f;
    int k = 0;
    for (; k + 1 < c; k += 2) {
        int2 p0 = b[k], p1 = b[k + 1];
        a0 += __int_as_float(p0.y) * __half2float(h1[(size_t)p0.x * F1 + j]);
        a1 += __int_as_float(p1.y) * __half2float(h1[(size_t)p1.x * F1 + j]);
    }
    if (k < c) {
        int2 p = b[k];
        a0 += __int_as_float(p.y) * __half2float(h1[(size_t)p.x * F1 + j]);
    }
    float di = dinv[node];
    float g = di * (a0 + a1 + __half2float(h1[(size_t)node * F1 + j])) + b1[j];
    g = fmaxf(g, 0.f);
    float hv[8];
#pragma unroll
    for (int cc = 0; cc < 8; ++cc) hv[cc] = g * sW[j * 9 + cc];
#pragma unroll
    for (int off = 1; off < 16; off <<= 1) {
#pragma unroll
        for (int cc = 0; cc < 8; ++cc) hv[cc] += __shfl_xor(hv[cc], off, 16);
    }
    float o = hv[0];
#pragma unroll
    for (int cc = 1; cc < 8; ++cc) if (j == cc) o = hv[cc];
    if (j < 8) h2[(size_t)node * 8 + j] = __float2half(di * o);
}

__global__ __launch_bounds__(256) void kf_gather2(
        const int* __restrict__ cur, const int2* __restrict__ ep,
        const __half* __restrict__ h2, const float* __restrict__ dinv,
        const float* __restrict__ b2, float* __restrict__ out, int n) {
    int t = threadIdx.x;
    int node = blockIdx.x * 32 + (t >> 3);
    int c = t & 7;
    if (node >= n) return;
    int cd = cur[node]; if (cd > CMAX) cd = CMAX;
    const int2* b = ep + (size_t)node * CMAX;
    float a0 = 0.f, a1 = 0.f;
    int k = 0;
    for (; k + 1 < cd; k += 2) {
        int2 p0 = b[k], p1 = b[k + 1];
        a0 += __int_as_float(p0.y) * __half2float(h2[(size_t)p0.x * 8 + c]);
        a1 += __int_as_float(p1.y) * __half2float(h2[(size_t)p1.x * 8 + c]);
    }
    if (k < cd) {
        int2 p = b[k];
        a0 += __int_as_float(p.y) * __half2float(h2[(size_t)p.x * 8 + c]);
    }
    float di = dinv[node];
    float v = di * (a0 + a1 + __half2float(h2[(size_t)node * 8 + c]))
              + ((c < F2) ? b2[c] : 0.f);
    float vm = (c < F2) ? v : -3.0e38f;
    vm = fmaxf(vm, __shfl_xor(vm, 1, 8));
    vm = fmaxf(vm, __shfl_xor(vm, 2, 8));
    vm = fmaxf(vm, __shfl_xor(vm, 4, 8));
    float ex = (c < F2) ? __expf(v - vm) : 0.f;
    float s = ex;
    s += __shfl_xor(s, 1, 8);
    s += __shfl_xor(s, 2, 8);
    s += __shfl_xor(s, 4, 8);
    float ls = __logf(s) + vm;
    if (c < F2) out[(size_t)node * F2 + c] = v - ls;
}

// ===========================================================================

extern "C" void kernel_launch(void* const* d_in, const int* in_sizes, int n_in,
                              void* d_out, int out_size, void* d_ws, size_t ws_size,
                              hipStream_t stream) {
    const float* x  = (const float*)d_in[0];
    const int* ei32 = (const int*)d_in[1];
    const long long* ei64 = (const long long*)d_in[1];
    const float* w  = (const float*)d_in[2];
    const float* W1 = (const float*)d_in[3];
    const float* b1 = (const float*)d_in[4];
    const float* W2 = (const float*)d_in[5];
    const float* b2 = (const float*)d_in[6];
    float* out = (float*)d_out;

    const int n = in_sizes[0] / F0;       // 100000
    const int E = in_sizes[2];            // 3200000
    const int B = 256;

    const int nbin = (n + NPB - 1) / NPB; // 782
    double mean = (double)E / (double)nbin;
    bool ok_bin = (n <= (1 << 17)) && (nbin <= NBMAX) &&
                  (mean + 8.0 * sqrt(mean) + 64.0 <= (double)BINCAP);

    size_t binrec_b = (size_t)nbin * BINCAP * sizeof(int2);
    size_t alias_b  = (size_t)n * (F1 + 8) * sizeof(__half);  // h1h + h2h
    size_t reg0     = binrec_b > alias_b ? binrec_b : alias_b;
    size_t need_bin = reg0 + (size_t)E * sizeof(int2)
                    + (size_t)n * 3 * 4 + (size_t)NBMAX * 8 + 256;

    if (ok_bin && ws_size >= need_bin) {
        // -------- binned counting-sort CSR path --------
        char* p = (char*)d_ws;
        int2* binrec = (int2*)p;                         // dead after kB_build
        __half* h1   = (__half*)p;                       // aliases binrec (3.2MB)
        __half* h2   = h1 + (size_t)n * F1;              // 1.6MB
        int2* ep     = (int2*)(p + reg0);                // E*8B
        float* dinv  = (float*)(ep + E);                 // n
        int* rp      = (int*)(dinv + n);                 // n
        int* cntn    = rp + n;                           // n
        int* gcnt    = cntn + n;                         // NBMAX
        int* gbase   = gcnt + NBMAX;                     // NBMAX
        int* flag    = gbase + NBMAX;                    // 1

        k_init2<<<1, 1024, 0, stream>>>(ei32, 2 * E, flag, gcnt);
        kA_bin<<<(E + CH - 1) / CH, 512, 0, stream>>>(
            ei32, ei64, flag, w, gcnt, binrec, E, nbin);
        kB_scanbins<<<1, 1024, 0, stream>>>(gcnt, gbase, nbin);
        kB_build<<<nbin, 512, 0, stream>>>(binrec, gcnt, gbase, ep, rp, cntn, dinv, n);
        k_gemm1<<<(n + 255) / 256, B, 0, stream>>>(x, W1, dinv, h1, n);
        kg1<<<(n + 15) / 16, B, 0, stream>>>(rp, cntn, ep, h1, dinv, b1, W2, h2, n);
        kg2<<<(n + 31) / 32, B, 0, stream>>>(rp, cntn, ep, h2, dinv, b2, out, n);
    } else {
        // -------- fallback: bucket CSR --------
        const int nbN = (n + B - 1) / B;
        const int nbE = (E + B - 1) / B;
        int2* ep    = (int2*)d_ws;                       // n*CMAX*8B
        __half* h1  = (__half*)(ep + (size_t)n * CMAX);  // n*16 halves
        __half* h2  = h1 + (size_t)n * F1;               // n*8 halves
        float* dinv = (float*)(h2 + (size_t)n * 8);      // n
        int* cur    = (int*)(dinv + n);                  // n
        int* flag   = cur + n;                           // 1

        kf_init<<<nbN, B, 0, stream>>>(ei32, 2 * E, flag, cur, n);
        kf_fill<<<nbE, B, 0, stream>>>(ei32, ei64, flag, w, cur, ep, E);
        kf_degdinv<<<(n + 15) / 16, B, 0, stream>>>(cur, ep, dinv, n);
        k_gemm1<<<(n + 255) / 256, B, 0, stream>>>(x, W1, dinv, h1, n);
        kf_gather1<<<(n + 15) / 16, B, 0, stream>>>(cur, ep, h1, dinv, b1, W2, h2, n);
        kf_gather2<<<(n + 31) / 32, B, 0, stream>>>(cur, ep, h2, dinv, b2, out, n);
    }
}